// Round 4
// baseline (44.176 us; speedup 1.0000x reference)
//
#include <hip/hip_runtime.h>
#include <float.h>

#define NPRED 8192
#define NGT   32768
#define BLK   256
#define P     8
#define NCHUNK (NPRED / (BLK * P))   // 4 pred chunks of 2048
#define NSEG   128
#define SEGLEN (NGT / NSEG)          // 256 gt points per segment
#define G      8                     // points per group = 4 pairs
#define NGRP   (SEGLEN / G)          // 32 groups
#define NPB    (NPRED / BLK)         // 32 finalize blocks

typedef float v2f __attribute__((ext_vector_type(2)));

// packed 2-wide fp32 fma: d.lo = a.lo*b.lo+c.lo ; d.hi = a.hi*b.hi+c.hi
// IEEE-identical per lane to v_fma_f32 -> scalar rescan matches bit-exactly.
__device__ __forceinline__ v2f pk_fma(v2f a, v2f b, v2f c) {
    v2f d;
    asm("v_pk_fma_f32 %0, %1, %2, %3" : "=v"(d) : "v"(a), "v"(b), "v"(c));
    return d;
}

// ws layout:
//   [0, NGT*16)            float4 gtp[NGT]  pair-packed:
//       pair m: gtp[2m]   = (-2x0, -2x1, -2y0, -2y1)
//               gtp[2m+1] = (-2z0, -2z1,  q0,   q1)   q = x^2+y^2+z^2
//   [+NGT*16, +NPRED*8)    u64 res[NPRED]  packed (scorekey<<32|idx)
//   [.., +NPB*8)           float2 bsums[NPB]

__global__ void prep_kernel(const float* __restrict__ gt, float4* __restrict__ gtp,
                            unsigned long long* __restrict__ res) {
    int m = blockIdx.x * blockDim.x + threadIdx.x;   // pair id < NGT/2
    const float* a = gt + (size_t)m * 12;
    float x0 = a[0], y0 = a[1], z0 = a[2];
    float x1 = a[6], y1 = a[7], z1 = a[8];
    gtp[m * 2 + 0] = make_float4(-2.0f * x0, -2.0f * x1, -2.0f * y0, -2.0f * y1);
    gtp[m * 2 + 1] = make_float4(-2.0f * z0, -2.0f * z1,
                                 x0 * x0 + y0 * y0 + z0 * z0,
                                 x1 * x1 + y1 * y1 + z1 * z1);
    if (m < NPRED) res[m] = 0xFFFFFFFFFFFFFFFFull;
}

__device__ __forceinline__ unsigned int fkey(float f) {
    unsigned int u = __float_as_uint(f);
    return u ^ (unsigned int)(((int)u >> 31) | 0x80000000);
}

__global__ __launch_bounds__(BLK, 2) void argmin_kernel(const float* __restrict__ pred,
                                                        const float4* __restrict__ gtp,
                                                        unsigned long long* __restrict__ res) {
    __shared__ float4 tile[SEGLEN];              // 256 float4 = 128 pairs = 4KB
    const int t = threadIdx.x;
    const int chunk = blockIdx.x;
    const int seg = blockIdx.y;
    const int j0 = seg * SEGLEN;

    tile[t] = gtp[seg * SEGLEN + t];

    v2f pX[P], pY[P], pZ[P];
    float best[P];
    int bg[P];
    const int pbase = chunk * (BLK * P) + t;
    #pragma unroll
    for (int k = 0; k < P; ++k) {
        const float* p = pred + (size_t)(pbase + k * BLK) * 6;
        float px = p[0], py = p[1], pz = p[2];
        pX[k] = (v2f){px, px}; pY[k] = (v2f){py, py}; pZ[k] = (v2f){pz, pz};
        best[k] = FLT_MAX; bg[k] = 0;
    }
    __syncthreads();

    #pragma unroll 2
    for (int grp = 0; grp < NGRP; ++grp) {
        const int base = grp * G;                // float4 index (8 per group)
        float4 A0 = tile[base + 0], B0 = tile[base + 1];
        float4 A1 = tile[base + 2], B1 = tile[base + 3];
        float4 A2 = tile[base + 4], B2 = tile[base + 5];
        float4 A3 = tile[base + 6], B3 = tile[base + 7];
        #pragma unroll
        for (int k = 0; k < P; ++k) {
            v2f s01 = pk_fma((v2f){A0.x, A0.y}, pX[k],
                      pk_fma((v2f){A0.z, A0.w}, pY[k],
                      pk_fma((v2f){B0.x, B0.y}, pZ[k], (v2f){B0.z, B0.w})));
            v2f s23 = pk_fma((v2f){A1.x, A1.y}, pX[k],
                      pk_fma((v2f){A1.z, A1.w}, pY[k],
                      pk_fma((v2f){B1.x, B1.y}, pZ[k], (v2f){B1.z, B1.w})));
            v2f s45 = pk_fma((v2f){A2.x, A2.y}, pX[k],
                      pk_fma((v2f){A2.z, A2.w}, pY[k],
                      pk_fma((v2f){B2.x, B2.y}, pZ[k], (v2f){B2.z, B2.w})));
            v2f s67 = pk_fma((v2f){A3.x, A3.y}, pX[k],
                      pk_fma((v2f){A3.z, A3.w}, pY[k],
                      pk_fma((v2f){B3.x, B3.y}, pZ[k], (v2f){B3.z, B3.w})));
            float t0 = fminf(fminf(s01.x, s01.y), s23.x);   // v_min3
            float t1 = fminf(fminf(s23.y, s45.x), s45.y);   // v_min3
            float t2 = fminf(fminf(s67.x, s67.y), t0);      // v_min3
            float m  = fminf(t1, t2);
            if (m < best[k]) { best[k] = m; bg[k] = grp; }  // strict <: earliest group
        }
    }

    // rescan winning group with scalar fma chain (bit-exact vs pk lanes)
    #pragma unroll
    for (int k = 0; k < P; ++k) {
        const int gb = bg[k] * G;
        float px = pX[k].x, py = pY[k].x, pz = pZ[k].x;
        float s[G];
        #pragma unroll
        for (int pr = 0; pr < G / 2; ++pr) {
            float4 A = tile[gb + pr * 2 + 0];
            float4 B = tile[gb + pr * 2 + 1];
            s[pr * 2 + 0] = fmaf(A.x, px, fmaf(A.z, py, fmaf(B.x, pz, B.z)));
            s[pr * 2 + 1] = fmaf(A.y, px, fmaf(A.w, py, fmaf(B.y, pz, B.w)));
        }
        int off = G - 1;
        #pragma unroll
        for (int o = G - 2; o >= 0; --o)
            if (s[o] == best[k]) off = o;                   // earliest match wins
        unsigned long long pk = ((unsigned long long)fkey(best[k]) << 32)
                              | (unsigned long long)(j0 + bg[k] * G + off);
        atomicMin(&res[pbase + k * BLK], pk);               // deterministic
    }
}

__global__ __launch_bounds__(BLK) void finalize_kernel(const float* __restrict__ pred,
                                                       const float* __restrict__ gt,
                                                       const unsigned long long* __restrict__ res,
                                                       float2* __restrict__ bsums) {
    int i = blockIdx.x * BLK + threadIdx.x;
    int bidx = (int)(res[i] & 0xFFFFFFFFull);

    const float* g = &gt[(size_t)bidx * 6];
    float gx = g[0], gy = g[1], gz = g[2];
    float gnx = g[3], gny = g[4], gnz = g[5];
    const float* p = &pred[(size_t)i * 6];
    float px = p[0], py = p[1], pz = p[2];
    float pnx = p[3], pny = p[4], pnz = p[5];

    float dx = px - gx, dy = py - gy, dz = pz - gz;
    float v1 = dx * dx + dy * dy + dz * dz;

    float pn = sqrtf(pnx * pnx + pny * pny + pnz * pnz);
    float gn = sqrtf(gnx * gnx + gny * gny + gnz * gnz);
    float denom = fmaxf(pn, 1e-4f) * fmaxf(gn, 1e-4f);
    float cosv = (pnx * gnx + pny * gny + pnz * gnz) / denom;
    float v2 = 1.0f - cosv;

    #pragma unroll
    for (int off = 32; off > 0; off >>= 1) {
        v1 += __shfl_down(v1, off);
        v2 += __shfl_down(v2, off);
    }
    __shared__ float s1[BLK / 64];
    __shared__ float s2[BLK / 64];
    int wid = threadIdx.x >> 6;
    if ((threadIdx.x & 63) == 0) { s1[wid] = v1; s2[wid] = v2; }
    __syncthreads();
    if (threadIdx.x == 0) {
        float a = 0.0f, b = 0.0f;
        #pragma unroll
        for (int w = 0; w < BLK / 64; ++w) { a += s1[w]; b += s2[w]; }
        bsums[blockIdx.x] = make_float2(a, b);
    }
}

__global__ void final_reduce_kernel(const float2* __restrict__ bsums, float* __restrict__ out) {
    int t = threadIdx.x;
    float v1 = 0.0f, v2 = 0.0f;
    if (t < NPB) { float2 r = bsums[t]; v1 = r.x; v2 = r.y; }
    #pragma unroll
    for (int off = 32; off > 0; off >>= 1) {
        v1 += __shfl_down(v1, off);
        v2 += __shfl_down(v2, off);
    }
    if (t == 0) out[0] = v1 / (NPRED * 3.0f) + v2 / (float)NPRED;
}

extern "C" void kernel_launch(void* const* d_in, const int* in_sizes, int n_in,
                              void* d_out, int out_size, void* d_ws, size_t ws_size,
                              hipStream_t stream) {
    const float* pred_feat = (const float*)d_in[0];
    const float* gt_data   = (const float*)d_in[3];
    float* out = (float*)d_out;

    char* ws = (char*)d_ws;
    float4* gtp = (float4*)ws;
    unsigned long long* res = (unsigned long long*)(ws + (size_t)NGT * 16);
    float2* bsums = (float2*)(ws + (size_t)NGT * 16 + (size_t)NPRED * 8);

    prep_kernel<<<(NGT / 2) / 256, 256, 0, stream>>>(gt_data, gtp, res);
    dim3 grid(NCHUNK, NSEG);
    argmin_kernel<<<grid, BLK, 0, stream>>>(pred_feat, gtp, res);
    finalize_kernel<<<NPB, BLK, 0, stream>>>(pred_feat, gt_data, res, bsums);
    final_reduce_kernel<<<1, 64, 0, stream>>>(bsums, out);
}

// Round 5
// 39.263 us; speedup vs baseline: 1.1251x; 1.1251x over previous
//
#include <hip/hip_runtime.h>
#include <float.h>

#define NPRED 8192
#define NGT   32768
#define BLK   256
#define P     4
#define NCHUNK (NPRED / (BLK * P))   // 8 pred chunks of 1024
#define NSEG   128
#define SEGLEN (NGT / NSEG)          // 256 gt points per segment (== BLK)
#define G      8                     // group size for min3 tree
#define NGRP   (SEGLEN / G)          // 32 groups, grp fits inline const
#define FBLK   256
#define NPB    (NPRED / FBLK)        // 32 finalize blocks

// ws layout:
//   [0, NGT*16)            float4 gt4[NGT] = (-2gx,-2gy,-2gz,g2)   512KB
//   [+NGT*16, +NPRED*8)    u64 res[NPRED]  packed (scorekey<<32|idx) 64KB
//   [.., +NPB*8)           u64 bsums[NPB]  (two packed f32)
//   [.., +4)               u32 counter

__global__ void prep_kernel(const float* __restrict__ gt, float4* __restrict__ gt4,
                            unsigned long long* __restrict__ res,
                            unsigned int* __restrict__ counter) {
    int j = blockIdx.x * blockDim.x + threadIdx.x;
    if (j < NGT) {
        float x = gt[j * 6 + 0], y = gt[j * 6 + 1], z = gt[j * 6 + 2];
        gt4[j] = make_float4(-2.0f * x, -2.0f * y, -2.0f * z, x * x + y * y + z * z);
    }
    if (j < NPRED) res[j] = 0xFFFFFFFFFFFFFFFFull;
    if (j == 0) *counter = 0u;
}

__device__ __forceinline__ unsigned int fkey(float f) {
    unsigned int u = __float_as_uint(f);
    return u ^ (unsigned int)(((int)u >> 31) | 0x80000000);
}

__device__ __forceinline__ float score(const float4& g, float px, float py, float pz) {
    // fixed fma chain: bit-exact reproducible at rescan
    return fmaf(g.x, px, fmaf(g.y, py, fmaf(g.z, pz, g.w)));
}

__global__ __launch_bounds__(BLK, 4) void argmin_kernel(const float* __restrict__ pred,
                                                        const float4* __restrict__ gt4,
                                                        unsigned long long* __restrict__ res) {
    __shared__ float4 tile[SEGLEN];              // 4KB
    const int t = threadIdx.x;
    const int chunk = blockIdx.x;
    const int seg = blockIdx.y;
    const int j0 = seg * SEGLEN;

    tile[t] = gt4[j0 + t];                       // SEGLEN == BLK

    float px[P], py[P], pz[P], best[P];
    int bg[P];
    const int pbase = chunk * (BLK * P) + t;
    #pragma unroll
    for (int k = 0; k < P; ++k) {
        const float* p = pred + (size_t)(pbase + k * BLK) * 6;
        px[k] = p[0]; py[k] = p[1]; pz[k] = p[2];
        best[k] = FLT_MAX; bg[k] = 0;
    }
    __syncthreads();

    #pragma unroll 1
    for (int grp = 0; grp < NGRP; ++grp) {
        const int base = grp * G;
        float4 g0 = tile[base + 0], g1 = tile[base + 1];
        float4 g2 = tile[base + 2], g3 = tile[base + 3];
        float4 g4 = tile[base + 4], g5 = tile[base + 5];
        float4 g6 = tile[base + 6], g7 = tile[base + 7];
        #pragma unroll
        for (int k = 0; k < P; ++k) {
            float s0 = score(g0, px[k], py[k], pz[k]);
            float s1 = score(g1, px[k], py[k], pz[k]);
            float s2 = score(g2, px[k], py[k], pz[k]);
            float s3 = score(g3, px[k], py[k], pz[k]);
            float s4 = score(g4, px[k], py[k], pz[k]);
            float s5 = score(g5, px[k], py[k], pz[k]);
            float s6 = score(g6, px[k], py[k], pz[k]);
            float s7 = score(g7, px[k], py[k], pz[k]);
            float t0 = fminf(fminf(s0, s1), s2);         // v_min3
            float t1 = fminf(fminf(s3, s4), s5);         // v_min3
            float t2 = fminf(fminf(s6, s7), t0);         // v_min3
            float m  = fminf(t1, t2);
            if (m < best[k]) { best[k] = m; bg[k] = grp; }  // strict <: earliest group
        }
    }

    // rescan winning group: identical fma chain -> bit-exact equality
    #pragma unroll
    for (int k = 0; k < P; ++k) {
        const int gb = bg[k] * G;
        float s[G];
        #pragma unroll
        for (int o = 0; o < G; ++o)
            s[o] = score(tile[gb + o], px[k], py[k], pz[k]);
        int off = G - 1;
        #pragma unroll
        for (int o = G - 2; o >= 0; --o)
            if (s[o] == best[k]) off = o;                // earliest match wins
        unsigned long long pk = ((unsigned long long)fkey(best[k]) << 32)
                              | (unsigned long long)(j0 + gb + off);
        atomicMin(&res[pbase + k * BLK], pk);            // deterministic
    }
}

__global__ __launch_bounds__(FBLK) void finalize_kernel(const float* __restrict__ pred,
                                                        const float* __restrict__ gt,
                                                        const unsigned long long* __restrict__ res,
                                                        unsigned long long* __restrict__ bsums,
                                                        unsigned int* __restrict__ counter,
                                                        float* __restrict__ out) {
    int i = blockIdx.x * FBLK + threadIdx.x;
    int bidx = (int)(res[i] & 0xFFFFFFFFull);

    const float* g = &gt[(size_t)bidx * 6];
    float gx = g[0], gy = g[1], gz = g[2];
    float gnx = g[3], gny = g[4], gnz = g[5];
    const float* p = &pred[(size_t)i * 6];
    float px = p[0], py = p[1], pz = p[2];
    float pnx = p[3], pny = p[4], pnz = p[5];

    float dx = px - gx, dy = py - gy, dz = pz - gz;
    float v1 = dx * dx + dy * dy + dz * dz;

    float pn = sqrtf(pnx * pnx + pny * pny + pnz * pnz);
    float gn = sqrtf(gnx * gnx + gny * gny + gnz * gnz);
    float denom = fmaxf(pn, 1e-4f) * fmaxf(gn, 1e-4f);
    float cosv = (pnx * gnx + pny * gny + pnz * gnz) / denom;
    float v2 = 1.0f - cosv;

    #pragma unroll
    for (int off = 32; off > 0; off >>= 1) {
        v1 += __shfl_down(v1, off);
        v2 += __shfl_down(v2, off);
    }
    __shared__ float s1[FBLK / 64];
    __shared__ float s2[FBLK / 64];
    __shared__ int lastFlag;
    int wid = threadIdx.x >> 6;
    if ((threadIdx.x & 63) == 0) { s1[wid] = v1; s2[wid] = v2; }
    __syncthreads();
    if (threadIdx.x == 0) {
        float a = 0.0f, b = 0.0f;
        #pragma unroll
        for (int w = 0; w < FBLK / 64; ++w) { a += s1[w]; b += s2[w]; }
        unsigned long long pk = (unsigned long long)__float_as_uint(a)
                              | ((unsigned long long)__float_as_uint(b) << 32);
        __hip_atomic_store(&bsums[blockIdx.x], pk, __ATOMIC_RELEASE, __HIP_MEMORY_SCOPE_AGENT);
        unsigned int tk = __hip_atomic_fetch_add(counter, 1u, __ATOMIC_ACQ_REL, __HIP_MEMORY_SCOPE_AGENT);
        lastFlag = (tk == NPB - 1) ? 1 : 0;
    }
    __syncthreads();
    if (lastFlag && threadIdx.x < 64) {
        float a = 0.0f, b = 0.0f;
        if (threadIdx.x < NPB) {
            unsigned long long pk = __hip_atomic_load(&bsums[threadIdx.x],
                                                      __ATOMIC_ACQUIRE, __HIP_MEMORY_SCOPE_AGENT);
            a = __uint_as_float((unsigned int)(pk & 0xFFFFFFFFull));
            b = __uint_as_float((unsigned int)(pk >> 32));
        }
        #pragma unroll
        for (int off = 32; off > 0; off >>= 1) {
            a += __shfl_down(a, off);
            b += __shfl_down(b, off);
        }
        if (threadIdx.x == 0) out[0] = a / (NPRED * 3.0f) + b / (float)NPRED;
    }
}

extern "C" void kernel_launch(void* const* d_in, const int* in_sizes, int n_in,
                              void* d_out, int out_size, void* d_ws, size_t ws_size,
                              hipStream_t stream) {
    const float* pred_feat = (const float*)d_in[0];
    const float* gt_data   = (const float*)d_in[3];
    float* out = (float*)d_out;

    char* ws = (char*)d_ws;
    float4* gt4 = (float4*)ws;
    unsigned long long* res = (unsigned long long*)(ws + (size_t)NGT * 16);
    unsigned long long* bsums = (unsigned long long*)(ws + (size_t)NGT * 16 + (size_t)NPRED * 8);
    unsigned int* counter = (unsigned int*)(ws + (size_t)NGT * 16 + (size_t)NPRED * 8 + (size_t)NPB * 8);

    prep_kernel<<<NGT / 256, 256, 0, stream>>>(gt_data, gt4, res, counter);
    dim3 grid(NCHUNK, NSEG);
    argmin_kernel<<<grid, BLK, 0, stream>>>(pred_feat, gt4, res);
    finalize_kernel<<<NPB, FBLK, 0, stream>>>(pred_feat, gt_data, res, bsums, counter, out);
}